// Round 1
// baseline (1279.521 us; speedup 1.0000x reference)
//
#include <hip/hip_runtime.h>
#include <math.h>

// Problem constants (match reference)
#define BATCH 1024
#define NV    64      // N_VARS
#define MC    256     // M_CLAUSES
#define KD    12      // K_DIM
#define CSTR  68      // padded row stride for C (65 cols used), 16B-aligned rows
#define PI_F  3.14159265358979323846f

// ---- DPP helpers: 16-lane all-reduce (sum) with zero DS ops -----------------
// quad_perm [1,0,3,2] = 0xB1 (xor1), quad_perm [2,3,0,1] = 0x4E (xor2),
// row_ror:4 = 0x124, row_ror:8 = 0x128. After the two quad_perms values are
// quad-uniform, so the rotations complete a full 16-lane all-reduce.
template <int CTRL>
__device__ __forceinline__ float dpp_addf(float x) {
  int y = __builtin_amdgcn_update_dpp(0, __float_as_int(x), CTRL, 0xF, 0xF, false);
  return x + __int_as_float(y);
}

__device__ __forceinline__ float allreduce16(float x) {
  x = dpp_addf<0xB1>(x);
  x = dpp_addf<0x4E>(x);
  x = dpp_addf<0x124>(x);
  x = dpp_addf<0x128>(x);
  return x;
}

// ---- Kernel 1: C = Sw^T Sw, Sw = S * w[:,None]  (65x65, shared by batch) ----
__global__ void compute_C_kernel(const float* __restrict__ S,
                                 const float* __restrict__ w,
                                 float* __restrict__ C) {
  const int i = blockIdx.x;   // 0..64
  const int j = threadIdx.x;  // 0..127 (active < 65)
  if (j >= NV + 1) return;
  float acc = 0.f;
  for (int m = 0; m < MC; ++m) {
    const float wm = w[m];
    const float si = S[m * (NV + 1) + i];  // broadcast across threads
    const float sj = S[m * (NV + 1) + j];  // coalesced
    acc = fmaf(si * wm * wm, sj, acc);     // (si*w)*(sj*w)
  }
  C[i * CSTR + j] = acc;
}

// ---- Kernel 2: the mixing iteration ----------------------------------------
// Layout: 64 threads/block = 1 wave = 4 batch elements.
// lane = (b_local<<4) | k, k in 0..15 (12 valid; pad lanes stay exactly 0).
// Per lane: V[n][k] for n=1..64 in 64 registers (i-loop fully unrolled).
// C row entries are wave-uniform -> scalar loads (s_load) -> sgpr fmac operand.
__global__ __launch_bounds__(64) void mixing_kernel(
    const float* __restrict__ z, const float* __restrict__ r,
    const float* __restrict__ C, const int* __restrict__ max_iter_p,
    float* __restrict__ out) {
  const int t = threadIdx.x;
  const int k = t & 15;
  const int b = blockIdx.x * 4 + (t >> 4);
  const float mask0 = (k == 0) ? 1.f : 0.f;
  const int max_iter = max_iter_p[0];

  float V[NV];  // V[n][my k], n = idx+1 (row 0 is the constant e0, handled via mask0)

  // ---- init: V[n] = -cos(pi z) e0 + sin(pi z) * r_perp_hat ----
  #pragma unroll
  for (int n = 0; n < NV; ++n) {
    const float zv = z[b * NV + n];
    const float rv = (k < KD) ? r[(b * NV + n) * KD + k] : 0.f;
    const float rp = (k == 0) ? 0.f : rv;  // component 0 zeroed before normalize
    const float ss = allreduce16(rp * rp);
    const float inv = 1.f / fmaxf(sqrtf(ss), 1e-8f);
    float s, c;
    sincosf(PI_F * zv, &s, &c);
    V[n] = fmaf(-c, mask0, s * rp * inv);  // pad lanes (k>=12): exactly 0
  }

  // ---- sweeps: g_i = sum_{n != i} C[i,n] V[n];  V[i] = -g/||g|| ----
  for (int it = 0; it < max_iter; ++it) {
    #pragma unroll
    for (int i = 1; i <= NV; ++i) {
      const float* crow = C + i * CSTR;
      float acc[4];
      acc[0] = mask0 * crow[0];  // n=0 term: V[0] = e0, contributes only to k=0
      acc[1] = 0.f; acc[2] = 0.f; acc[3] = 0.f;
      #pragma unroll
      for (int n = 1; n <= NV; ++n) {
        if (n != i) acc[n & 3] = fmaf(crow[n], V[n - 1], acc[n & 3]);
      }
      const float g = (acc[0] + acc[1]) + (acc[2] + acc[3]);
      const float n2 = allreduce16(g * g);
      // -g / max(||g||, 1e-8)  ==  -g * rsqrt(max(n2, 1e-16))
      const float inv = rsqrtf(fmaxf(n2, 1e-16f));
      V[i - 1] = -g * inv;
    }
  }

  // ---- epilogue: out[b,n] = arccos(clip(-V[n,0])) / pi  (k==0 lanes only) ----
  if (k == 0) {
    #pragma unroll
    for (int n = 0; n < NV; ++n) {
      float cv = -V[n];
      cv = fminf(fmaxf(cv, -1.f + 1e-6f), 1.f - 1e-6f);
      out[b * NV + n] = acosf(cv) * (1.f / PI_F);
    }
  }
}

extern "C" void kernel_launch(void* const* d_in, const int* in_sizes, int n_in,
                              void* d_out, int out_size, void* d_ws, size_t ws_size,
                              hipStream_t stream) {
  const float* z = (const float*)d_in[0];
  const float* S = (const float*)d_in[1];
  const float* w = (const float*)d_in[2];
  const float* r = (const float*)d_in[3];
  const int* max_iter = (const int*)d_in[4];
  float* C = (float*)d_ws;  // 65 * CSTR * 4 = 17.7 KB scratch

  compute_C_kernel<<<NV + 1, 128, 0, stream>>>(S, w, C);
  mixing_kernel<<<BATCH / 4, 64, 0, stream>>>(z, r, C, max_iter, (float*)d_out);
}

// Round 2
// 803.638 us; speedup vs baseline: 1.5922x; 1.5922x over previous
//
#include <hip/hip_runtime.h>
#include <math.h>

// Problem constants (match reference)
#define BATCH 1024
#define NV    64      // N_VARS
#define MC    256     // M_CLAUSES
#define KD    12      // K_DIM
#define CSTR  68      // padded row stride (floats): slots 0..63 = cols 1..64,
                      // slot 64 = col 0, 65..67 pad. 272 B rows (16B aligned).
#define PI_F  3.14159265358979323846f

// ---- DPP helpers: 16-lane all-reduce (sum), zero DS ops ---------------------
template <int CTRL>
__device__ __forceinline__ float dpp_addf(float x) {
  int y = __builtin_amdgcn_update_dpp(0, __float_as_int(x), CTRL, 0xF, 0xF, false);
  return x + __int_as_float(y);
}
__device__ __forceinline__ float allreduce16(float x) {
  x = dpp_addf<0xB1>(x);   // quad_perm xor1
  x = dpp_addf<0x4E>(x);   // quad_perm xor2
  x = dpp_addf<0x124>(x);  // row_ror:4
  x = dpp_addf<0x128>(x);  // row_ror:8
  return x;
}

// ---- Kernel 1: rearranged Gram rows. Row (i-1) of Cg holds C[i][*]:
//   slot j   (j=0..63) = C[i][j+1]   (cols 1..64, contiguous for float4)
//   slot 64            = C[i][0]
// where C = Sw^T Sw, Sw = S * w[:,None]. Only rows i=1..64 are needed.
__global__ void compute_C_kernel(const float* __restrict__ S,
                                 const float* __restrict__ w,
                                 float* __restrict__ Cg) {
  const int i = blockIdx.x + 1;  // 1..64
  const int j = threadIdx.x;     // 0..127, active <= 64
  if (j > NV) return;
  float acc = 0.f;
  for (int m = 0; m < MC; ++m) {
    const float wm = w[m];
    const float si = S[m * (NV + 1) + i];
    const float sj = S[m * (NV + 1) + j];
    acc = fmaf(si * wm * wm, sj, acc);
  }
  const int jj = (j == 0) ? 64 : (j - 1);
  Cg[(i - 1) * CSTR + jj] = acc;
}

// ---- Kernel 2: the mixing iteration ----------------------------------------
// 64 threads/block = 1 wave = 4 batch elements; lane = (b_local<<4)|k, k in
// 0..15 (12 valid, pad lanes carry exact zeros). V[n][k] for n=1..64 lives in
// 64 VGPRs (fully static indexing). C rows live in LDS; per-step reads are
// wave-uniform addresses -> broadcast, conflict-free.
__global__ __launch_bounds__(64, 1) void mixing_kernel(
    const float* __restrict__ z, const float* __restrict__ r,
    const float* __restrict__ Cg, const int* __restrict__ max_iter_p,
    float* __restrict__ out) {
  __shared__ float Ls[NV * CSTR];  // 17408 B

  const int t = threadIdx.x;
  const int k = t & 15;
  const int b = blockIdx.x * 4 + (t >> 4);
  const float mask0 = (k == 0) ? 1.f : 0.f;
  const int max_iter = max_iter_p[0];

  // stage C into LDS (coalesced float4 copy; 17 iters/thread)
  {
    const float4* src = (const float4*)Cg;
    float4* dst = (float4*)Ls;
    #pragma unroll
    for (int idx = 0; idx < NV * CSTR / 4; idx += 64) dst[idx + t] = src[idx + t];
  }

  float V[NV];  // V[n][my k], n = index+1 (row 0 = e0 handled via mask0)

  // ---- init: V[n] = -cos(pi z) e0 + sin(pi z) * r_perp_hat ----
  #pragma unroll
  for (int n = 0; n < NV; ++n) {
    const float zv = z[b * NV + n];
    const float rv = (k < KD) ? r[(b * NV + n) * KD + k] : 0.f;
    const float rp = (k == 0) ? 0.f : rv;
    const float ss = allreduce16(rp * rp);
    const float inv = 1.f / fmaxf(sqrtf(ss), 1e-8f);
    float s, c;
    sincosf(PI_F * zv, &s, &c);
    V[n] = fmaf(-c, mask0, s * rp * inv);
  }

  __syncthreads();

  // ---- sweeps: g_i = sum_n C[i,n] V[n] - C[i,i] V[i];  V[i] = -g/||g|| ----
  for (int it = 0; it < max_iter; ++it) {
    #pragma unroll
    for (int i = 1; i <= NV; ++i) {
      const float* row = Ls + (i - 1) * CSTR;
      const float4* row4 = (const float4*)row;
      float acc0 = mask0 * row[64];  // col-0 term: V[0]=e0 hits only k==0
      float acc1 = 0.f, acc2 = 0.f, acc3 = 0.f;
      #pragma unroll
      for (int j = 0; j < 16; ++j) {
        const float4 c = row4[j];
        acc0 = fmaf(c.x, V[4 * j + 0], acc0);
        acc1 = fmaf(c.y, V[4 * j + 1], acc1);
        acc2 = fmaf(c.z, V[4 * j + 2], acc2);
        acc3 = fmaf(c.w, V[4 * j + 3], acc3);
      }
      float g = (acc0 + acc1) + (acc2 + acc3);
      g = fmaf(-row[i - 1], V[i - 1], g);  // remove diagonal C[i,i]*v_old
      const float n2 = allreduce16(g * g);
      const float inv = rsqrtf(fmaxf(n2, 1e-16f));  // == -g/max(||g||,1e-8)
      V[i - 1] = -g * inv;
    }
  }

  // ---- epilogue: out[b,n] = arccos(clip(-V[n,0])) / pi  (k==0 lanes) ----
  if (k == 0) {
    #pragma unroll
    for (int n = 0; n < NV; ++n) {
      float cv = -V[n];
      cv = fminf(fmaxf(cv, -1.f + 1e-6f), 1.f - 1e-6f);
      out[b * NV + n] = acosf(cv) * (1.f / PI_F);
    }
  }
}

extern "C" void kernel_launch(void* const* d_in, const int* in_sizes, int n_in,
                              void* d_out, int out_size, void* d_ws, size_t ws_size,
                              hipStream_t stream) {
  const float* z = (const float*)d_in[0];
  const float* S = (const float*)d_in[1];
  const float* w = (const float*)d_in[2];
  const float* r = (const float*)d_in[3];
  const int* max_iter = (const int*)d_in[4];
  float* Cg = (float*)d_ws;  // 64 * 68 * 4 = 17408 B scratch

  compute_C_kernel<<<NV, 128, 0, stream>>>(S, w, Cg);
  mixing_kernel<<<BATCH / 4, 64, 0, stream>>>(z, r, Cg, max_iter, (float*)d_out);
}